// Round 8
// baseline (185.454 us; speedup 1.0000x reference)
//
#include <hip/hip_runtime.h>
#include <math.h>

#define NSEQ 4096
#define EDIM 512
#define NHEAD 8
#define DHEAD 64

typedef unsigned short ushort_t;
typedef __attribute__((ext_vector_type(8))) _Float16 half8;    // 8 f16 (4 VGPRs)
typedef __attribute__((ext_vector_type(2))) __fp16 pkhalf2;    // cvt_pkrtz out
typedef __attribute__((ext_vector_type(4))) float floatx4;     // MFMA C/D
typedef __attribute__((ext_vector_type(8))) ushort_t us8;
typedef __attribute__((ext_vector_type(4))) ushort_t us4;

#define C2SCALE 0.02254211f  // log2(e)/64, folded into Q at projection

__device__ __forceinline__ ushort_t f2h(float x) {  // RNE float->f16
  union { _Float16 h; ushort_t u; } v;
  v.h = (_Float16)x;
  return v.u;
}

#if __has_builtin(__builtin_amdgcn_exp2f)
#define EXP2F(x) __builtin_amdgcn_exp2f(x)
#else
#define EXP2F(x) exp2f(x)
#endif

// ---------------------------------------------------------------------------
// fused fp32 -> f16 cast for inp (2048 blocks) + 4 weight mats (1024 blocks)
// ---------------------------------------------------------------------------
__global__ __launch_bounds__(256) void cast_all(
    const float* __restrict__ inp, ushort_t* __restrict__ Xf,
    const float* __restrict__ w0, const float* __restrict__ w1,
    const float* __restrict__ w2, const float* __restrict__ w3,
    ushort_t* __restrict__ d0, ushort_t* __restrict__ d1,
    ushort_t* __restrict__ d2, ushort_t* __restrict__ d3) {
  const int bid = blockIdx.x;
  const float* s;
  ushort_t* d;
  int blk;
  if (bid < 2048) {
    s = inp; d = Xf; blk = bid;
  } else {
    const int seg = (bid - 2048) >> 8;
    blk = (bid - 2048) & 255;
    switch (seg) {
      case 0: s = w0; d = d0; break;
      case 1: s = w1; d = d1; break;
      case 2: s = w2; d = d2; break;
      default: s = w3; d = d3; break;
    }
  }
  const int i = (blk * 256 + threadIdx.x) * 4;
  const float4 v = *(const float4*)(s + i);
  us4 o;
  o[0] = f2h(v.x); o[1] = f2h(v.y); o[2] = f2h(v.z); o[3] = f2h(v.w);
  *(us4*)(d + i) = o;
}

// ---------------------------------------------------------------------------
// Fused QKV f16 MFMA NT GEMM, LDS-staged, BK=64. 64o x 128n tile.
// z=0: Q -> f16 (E,N) scaled by C2SCALE; z=2: V -> f16 (E,N);
// z=1: K -> FRAGMENT-TILED layout:
//   elem (h, m, d) stored at h*262144 + ((m>>4)*2 + (d>>5))*512
//                            + ((m&15) + 16*((d&31)>>3))*8 + (d&7)
//   so an attention A-operand fragment (16 m x 32 d) is one contiguous 1KB run.
// ---------------------------------------------------------------------------
__global__ __launch_bounds__(256, 3) void gemm_qkv(
    const ushort_t* __restrict__ WQf, const float* __restrict__ WQb,
    const ushort_t* __restrict__ WKf, const float* __restrict__ WKb,
    const ushort_t* __restrict__ WVf, const float* __restrict__ WVb,
    const ushort_t* __restrict__ Xf, ushort_t* __restrict__ Qb,
    ushort_t* __restrict__ Kb, ushort_t* __restrict__ Vb) {
  __shared__ __align__(16) char smem[27648];
  ushort_t(*Ws)[72] = (ushort_t(*)[72])smem;           // [64][72]
  ushort_t(*Xs)[72] = (ushort_t(*)[72])(smem + 9216);  // [128][72]

  const int tid = threadIdx.x;
  const int w = tid >> 6, lane = tid & 63, quad = lane >> 4, l16 = lane & 15;
  const int o0 = blockIdx.y * 64, n0 = blockIdx.x * 128, z = blockIdx.z;
  const int wr = tid >> 2, wseg = (tid & 3) * 16;  // W stage: 64 rows x 16 k
  const int xr = tid >> 1, xseg = (tid & 1) * 32;  // X stage: 128 rows x 32 k

  const ushort_t* Wf = (z == 0) ? WQf : (z == 1) ? WKf : WVf;
  const float* bias = (z == 0) ? WQb : (z == 1) ? WKb : WVb;

  floatx4 acc[4][2];
#pragma unroll
  for (int ot = 0; ot < 4; ++ot)
#pragma unroll
    for (int nt = 0; nt < 2; ++nt) {
      acc[ot][nt][0] = 0.f; acc[ot][nt][1] = 0.f;
      acc[ot][nt][2] = 0.f; acc[ot][nt][3] = 0.f;
    }

  for (int k0 = 0; k0 < EDIM; k0 += 64) {
    const us8 w0 = *(const us8*)(Wf + (o0 + wr) * 512 + k0 + wseg);
    const us8 w1 = *(const us8*)(Wf + (o0 + wr) * 512 + k0 + wseg + 8);
    us8 xv[4];
#pragma unroll
    for (int j = 0; j < 4; ++j)
      xv[j] = *(const us8*)(Xf + (n0 + xr) * 512 + k0 + xseg + j * 8);
    __syncthreads();  // previous iteration's LDS reads complete
    *(us8*)&Ws[wr][wseg] = w0;
    *(us8*)&Ws[wr][wseg + 8] = w1;
#pragma unroll
    for (int j = 0; j < 4; ++j) *(us8*)&Xs[xr][xseg + j * 8] = xv[j];
    __syncthreads();

    half8 a[2][4], b[2][2];
#pragma unroll
    for (int kh = 0; kh < 2; ++kh) {
#pragma unroll
      for (int ot = 0; ot < 4; ++ot)
        a[kh][ot] = *(const half8*)&Ws[ot * 16 + l16][kh * 32 + quad * 8];
#pragma unroll
      for (int nt = 0; nt < 2; ++nt)
        b[kh][nt] =
            *(const half8*)&Xs[w * 32 + nt * 16 + l16][kh * 32 + quad * 8];
    }
#pragma unroll
    for (int kh = 0; kh < 2; ++kh)
#pragma unroll
      for (int ot = 0; ot < 4; ++ot)
#pragma unroll
        for (int nt = 0; nt < 2; ++nt)
          acc[ot][nt] = __builtin_amdgcn_mfma_f32_16x16x32_f16(
              a[kh][ot], b[kh][nt], acc[ot][nt], 0, 0, 0);
  }

  __syncthreads();  // staging reads done; smem reused for epilogue
  float bo[4][4];
#pragma unroll
  for (int ot = 0; ot < 4; ++ot)
#pragma unroll
    for (int r = 0; r < 4; ++r)
      bo[ot][r] = bias[o0 + ot * 16 + quad * 4 + r];

  if (z != 1) {  // f16 (E,N): Q (scaled) or V
    ushort_t(*Cs)[136] = (ushort_t(*)[136])smem;
    const float scale = (z == 0) ? C2SCALE : 1.0f;
#pragma unroll
    for (int ot = 0; ot < 4; ++ot)
#pragma unroll
      for (int nt = 0; nt < 2; ++nt)
#pragma unroll
        for (int r = 0; r < 4; ++r)
          Cs[ot * 16 + quad * 4 + r][w * 32 + nt * 16 + l16] =
              f2h((acc[ot][nt][r] + bo[ot][r]) * scale);
    __syncthreads();
    ushort_t* C = (z == 0) ? Qb : Vb;
    const int row = tid >> 2, seg = (tid & 3) * 32;
#pragma unroll
    for (int j = 0; j < 4; ++j)
      *(us8*)(C + (o0 + row) * 4096 + n0 + seg + j * 8) =
          *(const us8*)&Cs[row][seg + j * 8];
  } else {  // K: fragment-tiled emit. Cs = [m 128][d 64] stride 72.
    ushort_t(*Cs)[72] = (ushort_t(*)[72])smem;
#pragma unroll
    for (int ot = 0; ot < 4; ++ot)
#pragma unroll
      for (int nt = 0; nt < 2; ++nt)
#pragma unroll
        for (int r = 0; r < 4; ++r)
          Cs[w * 32 + nt * 16 + l16][ot * 16 + quad * 4 + r] =
              f2h(acc[ot][nt][r] + bo[ot][r]);
    __syncthreads();
    const int h = blockIdx.y;            // o0>>6
    const int base_mt = n0 >> 4;         // m-16-group base
#pragma unroll
    for (int t = 0; t < 4; ++t) {
      const int c = tid + t * 256;       // 0..1023 us8-chunks
      const int mt = c >> 7;             // 0..7
      const int kh = (c >> 6) & 1;
      const int l = c & 63;
      const int mrow = mt * 16 + (l & 15);
      const int dcol = kh * 32 + ((l >> 4) & 3) * 8;
      *(us8*)(Kb + ((h * 256 + base_mt + mt) * 2 + kh) * 512 + l * 8) =
          *(const us8*)&Cs[mrow][dcol];
    }
  }
}

// ---------------------------------------------------------------------------
// Output projection: single-plane f16 in, fp32 (N,E) out. BK=64, 64x64 tile.
// ---------------------------------------------------------------------------
__global__ __launch_bounds__(256, 2) void gemm_out(
    const ushort_t* __restrict__ Wf, const ushort_t* __restrict__ Zf,
    const float* __restrict__ bias, float* __restrict__ C) {
  __shared__ __align__(16) char smem[18432];
  ushort_t(*Ws)[72] = (ushort_t(*)[72])smem;           // [64][72]
  ushort_t(*Xs)[72] = (ushort_t(*)[72])(smem + 9216);  // [64][72]

  const int tid = threadIdx.x;
  const int w = tid >> 6, lane = tid & 63, quad = lane >> 4, l16 = lane & 15;
  const int o0 = blockIdx.y * 64, n0 = blockIdx.x * 64;
  const int lr = tid >> 2, lseg = (tid & 3) * 16;

  floatx4 acc[4];
#pragma unroll
  for (int ot = 0; ot < 4; ++ot) {
    acc[ot][0] = 0.f; acc[ot][1] = 0.f; acc[ot][2] = 0.f; acc[ot][3] = 0.f;
  }

  for (int k0 = 0; k0 < EDIM; k0 += 64) {
    const us8 w0 = *(const us8*)(Wf + (o0 + lr) * 512 + k0 + lseg);
    const us8 w1 = *(const us8*)(Wf + (o0 + lr) * 512 + k0 + lseg + 8);
    const us8 x0 = *(const us8*)(Zf + (n0 + lr) * 512 + k0 + lseg);
    const us8 x1 = *(const us8*)(Zf + (n0 + lr) * 512 + k0 + lseg + 8);
    __syncthreads();
    *(us8*)&Ws[lr][lseg] = w0;
    *(us8*)&Ws[lr][lseg + 8] = w1;
    *(us8*)&Xs[lr][lseg] = x0;
    *(us8*)&Xs[lr][lseg + 8] = x1;
    __syncthreads();

    half8 a[2][4], b[2];
#pragma unroll
    for (int kh = 0; kh < 2; ++kh) {
#pragma unroll
      for (int ot = 0; ot < 4; ++ot)
        a[kh][ot] = *(const half8*)&Ws[ot * 16 + l16][kh * 32 + quad * 8];
      b[kh] = *(const half8*)&Xs[w * 16 + l16][kh * 32 + quad * 8];
    }
#pragma unroll
    for (int kh = 0; kh < 2; ++kh)
#pragma unroll
      for (int ot = 0; ot < 4; ++ot)
        acc[ot] = __builtin_amdgcn_mfma_f32_16x16x32_f16(a[kh][ot], b[kh],
                                                         acc[ot], 0, 0, 0);
  }

  __syncthreads();
  float(*Cs)[68] = (float(*)[68])smem;
#pragma unroll
  for (int ot = 0; ot < 4; ++ot) {
    floatx4 v = acc[ot];
#pragma unroll
    for (int r = 0; r < 4; ++r) v[r] += bias[o0 + ot * 16 + quad * 4 + r];
    *(floatx4*)&Cs[w * 16 + l16][ot * 16 + quad * 4] = v;
  }
  __syncthreads();
  const int row = tid >> 2, seg = (tid & 3) * 16;
#pragma unroll
  for (int j = 0; j < 4; ++j)
    *(float4*)(C + (n0 + row) * 512 + o0 + seg + j * 4) =
        *(const float4*)&Cs[row][seg + j * 4];
}

// ---------------------------------------------------------------------------
// V (f16, scrambled (E,N): elem (h,m,d) at h*262144 + m*64 + d)
//   -> fragment-tiled V^T: frag unit = 16 d x 32 m (A-operand for PV):
//   elem (h,d,m) at h*262144 + ((m>>5)*4 + (d>>4))*512
//                  + ((d&15) + 16*((m&31)>>3))*8 + (m&7)
// ---------------------------------------------------------------------------
__global__ __launch_bounds__(256) void transpose_v(
    const ushort_t* __restrict__ Vb, ushort_t* __restrict__ Vt) {
  __shared__ ushort_t Ts[64][72];
  const int tid = threadIdx.x;
  const int h = blockIdx.y;
  const int m0 = blockIdx.x * 64;
  const ushort_t* src = Vb + h * 262144 + m0 * 64;
  {
    const int r = tid >> 2, c = (tid & 3) << 4;
    const us8 a = *(const us8*)(src + r * 64 + c);
    const us8 b = *(const us8*)(src + r * 64 + c + 8);
    *(us8*)&Ts[r][c] = a;
    *(us8*)&Ts[r][c + 8] = b;
  }
  __syncthreads();
#pragma unroll
  for (int t = 0; t < 2; ++t) {
    const int c = tid + t * 256;  // 0..511 us8-chunks
    const int f = c >> 6;         // frag: mg*4 + dt
    const int mg = f >> 2, dt = f & 3;
    const int l = c & 63;
    const int mrow = mg * 32 + ((l >> 4) & 3) * 8;
    const int d = dt * 16 + (l & 15);
    us8 v;
#pragma unroll
    for (int j = 0; j < 8; ++j) v[j] = Ts[mrow + j][d];
    *(us8*)(Vt + h * 262144 + (((m0 >> 5) + mg) * 4 + dt) * 512 + l * 8) = v;
  }
}

// ---------------------------------------------------------------------------
// Flash attention v6: BARRIER-FREE K-loop. K and V^T pre-tiled in global in
// MFMA A-operand fragment order -> each frag = one coalesced 1KB/wave load.
// Only LDS use: per-wave P round-trip (C-layout -> A/B-layout). Max-free
// softmax (Q pre-scaled by log2(e)/64); rowsum in VALU (quad-partial + 2
// shfl_xor at end). Split-K 2 (blockIdx.z).
// ---------------------------------------------------------------------------
__global__ __launch_bounds__(256, 2) void attn_mfma(
    const ushort_t* __restrict__ Qb, const ushort_t* __restrict__ Kb,
    const ushort_t* __restrict__ Vt, ushort_t* __restrict__ Zp,
    float* __restrict__ Lp) {
  __shared__ __align__(16) ushort_t Ps[8][16][136];  // per (w,qt): P [n][m]

  const int tid = threadIdx.x;
  const int w = tid >> 6;
  const int lane = tid & 63;
  const int quad = lane >> 4;
  const int l16 = lane & 15;
  const int h = blockIdx.y;
  const int n0 = blockIdx.x * 128;
  const int z = blockIdx.z;
  const int mbase = z * (NSEQ / 2);

  // Q fragments (B-operand rows n = n0 + w*32 + qt*16 + l16, k=d contiguous)
  half8 qf[2][2];
#pragma unroll
  for (int qt = 0; qt < 2; ++qt) {
    const ushort_t* qsrc = Qb + h * 262144 + (n0 + w * 32 + qt * 16 + l16) * 64;
    qf[qt][0] = *(const half8*)(qsrc + quad * 8);
    qf[qt][1] = *(const half8*)(qsrc + 32 + quad * 8);
  }

  floatx4 zacc[2][4];
  float sl[2] = {0.f, 0.f};
#pragma unroll
  for (int qt = 0; qt < 2; ++qt)
#pragma unroll
    for (int dt = 0; dt < 4; ++dt) {
      zacc[qt][dt][0] = 0.f; zacc[qt][dt][1] = 0.f;
      zacc[qt][dt][2] = 0.f; zacc[qt][dt][3] = 0.f;
    }

  const ushort_t* kbase0 =
      Kb + h * 262144 + (mbase >> 4) * 1024 + lane * 8;
  const ushort_t* vbase0 =
      Vt + h * 262144 + (mbase >> 5) * 2048 + lane * 8;

  for (int m0 = 0; m0 < NSEQ / 2; m0 += 128) {
    // ---- K fragments direct from tiled global: 16 coalesced 1KB loads ----
    const ushort_t* kbase = kbase0 + (m0 >> 4) * 1024;
    half8 kf0[8], kf1[8];
#pragma unroll
    for (int mt = 0; mt < 8; ++mt) {
      kf0[mt] = *(const half8*)(kbase + mt * 1024);
      kf1[mt] = *(const half8*)(kbase + mt * 1024 + 512);
    }

    // ---- S^T = K Q^T; P = exp2(S^T) packed to Ps[n][m]; VALU rowsum ----
#pragma unroll
    for (int qt = 0; qt < 2; ++qt) {
#pragma unroll
      for (int mt = 0; mt < 8; ++mt) {
        floatx4 s = {0.f, 0.f, 0.f, 0.f};
        s = __builtin_amdgcn_mfma_f32_16x16x32_f16(kf0[mt], qf[qt][0], s, 0, 0, 0);
        s = __builtin_amdgcn_mfma_f32_16x16x32_f16(kf1[mt], qf[qt][1], s, 0, 0, 0);
        const float e0 = EXP2F(s[0]), e1 = EXP2F(s[1]);
        const float e2 = EXP2F(s[2]), e3 = EXP2F(s[3]);
        sl[qt] += (e0 + e1) + (e2 + e3);
        union { pkhalf2 h; unsigned u; } p01, p23;
        p01.h = __builtin_amdgcn_cvt_pkrtz(e0, e1);
        p23.h = __builtin_amdgcn_cvt_pkrtz(e2, e3);
        *(unsigned*)&Ps[w * 2 + qt][l16][mt * 16 + quad * 4] = p01.u;
        *(unsigned*)&Ps[w * 2 + qt][l16][mt * 16 + quad * 4 + 2] = p23.u;
      }
    }
    // per-wave Ps: same-wave LDS RAW ordered via lgkmcnt (no barrier)

    // ---- Z^T += V^T P^T; V^T frags direct from tiled global ----
    const ushort_t* vbase = vbase0 + (m0 >> 5) * 2048;
#pragma unroll
    for (int kc2 = 0; kc2 < 4; ++kc2) {
      const half8 pf0 = *(const half8*)&Ps[w * 2][l16][kc2 * 32 + quad * 8];
      const half8 pf1 = *(const half8*)&Ps[w * 2 + 1][l16][kc2 * 32 + quad * 8];
#pragma unroll
      for (int dt = 0; dt < 4; ++dt) {
        const half8 vf = *(const half8*)(vbase + kc2 * 2048 + dt * 512);
        zacc[0][dt] = __builtin_amdgcn_mfma_f32_16x16x32_f16(vf, pf0, zacc[0][dt], 0, 0, 0);
        zacc[1][dt] = __builtin_amdgcn_mfma_f32_16x16x32_f16(vf, pf1, zacc[1][dt], 0, 0, 0);
      }
    }
  }

  // ---- epilogue: Z^T partials f16; rowsum via 2 shfl_xor (quad bits) ----
#pragma unroll
  for (int qt = 0; qt < 2; ++qt) {
    float s = sl[qt];
    s += __shfl_xor(s, 16, 64);
    s += __shfl_xor(s, 32, 64);
    const int n = n0 + w * 32 + qt * 16 + l16;
    ushort_t* dst = Zp + z * 2097152 + n * EDIM + h * 64;
#pragma unroll
    for (int dt = 0; dt < 4; ++dt) {
      us4 o;
#pragma unroll
      for (int r = 0; r < 4; ++r) o[r] = f2h(zacc[qt][dt][r]);
      *(us4*)(dst + dt * 16 + quad * 4) = o;
    }
    if (quad == 0) Lp[z * 32768 + h * 4096 + n] = s;
  }
}

// ---------------------------------------------------------------------------
// combine: Z = (Z0+Z1)/(l0+l1), emit single f16 plane for the output GEMM.
// ---------------------------------------------------------------------------
__global__ __launch_bounds__(256) void combine(const ushort_t* __restrict__ Zp,
                                               const float* __restrict__ Lp,
                                               ushort_t* __restrict__ Zf) {
  const int base = (blockIdx.x * 256 + threadIdx.x) * 8;
  const int n = base >> 9, e = base & 511, h = e >> 6;
  const float inv = 1.0f / (Lp[h * 4096 + n] + Lp[32768 + h * 4096 + n]);
  const half8 a = *(const half8*)(Zp + base);
  const half8 b = *(const half8*)(Zp + 2097152 + base);
  us8 o;
#pragma unroll
  for (int j = 0; j < 8; ++j)
    o[j] = f2h(((float)a[j] + (float)b[j]) * inv);
  *(us8*)(Zf + base) = o;
}

extern "C" void kernel_launch(void* const* d_in, const int* in_sizes, int n_in,
                              void* d_out, int out_size, void* d_ws,
                              size_t ws_size, hipStream_t stream) {
  const float* inp = (const float*)d_in[0];
  const float* WKw = (const float*)d_in[1];
  const float* WKb = (const float*)d_in[2];
  const float* WQw = (const float*)d_in[3];
  const float* WQb = (const float*)d_in[4];
  const float* WVw = (const float*)d_in[5];
  const float* WVb = (const float*)d_in[6];
  const float* WZw = (const float*)d_in[7];
  const float* WZb = (const float*)d_in[8];

  char* ws = (char*)d_ws;
  const size_t MB = 1 << 20;
  ushort_t* Xf = (ushort_t*)(ws);                        // 4MB; Zf after attn
  ushort_t* WQf = (ushort_t*)(ws + 4 * MB);              // 512KB each
  ushort_t* WKf = (ushort_t*)(ws + 4 * MB + 512 * 1024);
  ushort_t* WVf = (ushort_t*)(ws + 5 * MB);
  ushort_t* WZf = (ushort_t*)(ws + 5 * MB + 512 * 1024);
  ushort_t* Qb = (ushort_t*)(ws + 6 * MB);    // 4MB f16 (E,N) scrambled, *C2
  ushort_t* Kb = (ushort_t*)(ws + 10 * MB);   // 4MB f16 frag-tiled
  ushort_t* Vb = (ushort_t*)(ws + 14 * MB);   // 4MB f16 (E,N)
  ushort_t* Vtb = (ushort_t*)(ws + 18 * MB);  // 4MB f16 frag-tiled V^T
  ushort_t* Zp = (ushort_t*)(ws + 22 * MB);   // 8MB: [2][4096][512] f16
  float* Lp = (float*)(ws + 30 * MB);         // 256KB: [2][8][4096]

  cast_all<<<3072, 256, 0, stream>>>(inp, Xf, WKw, WQw, WVw, WZw, WKf, WQf,
                                     WVf, WZf);

  gemm_qkv<<<dim3(NSEQ / 128, EDIM / 64, 3), 256, 0, stream>>>(
      WQf, WQb, WKf, WKb, WVf, WVb, Xf, Qb, Kb, Vb);

  transpose_v<<<dim3(NSEQ / 64, NHEAD), 256, 0, stream>>>(Vb, Vtb);

  attn_mfma<<<dim3(NSEQ / 128, NHEAD, 2), 256, 0, stream>>>(Qb, Kb, Vtb, Zp,
                                                            Lp);

  combine<<<1024, 256, 0, stream>>>(Zp, Lp, Xf);

  gemm_out<<<dim3(NSEQ / 64, EDIM / 64), 256, 0, stream>>>(WZf, Xf, WZb,
                                                           (float*)d_out);
}

// Round 9
// 157.921 us; speedup vs baseline: 1.1743x; 1.1743x over previous
//
#include <hip/hip_runtime.h>
#include <math.h>

#define NSEQ 4096
#define EDIM 512
#define NHEAD 8
#define DHEAD 64

// LESSON (R4, R8): direct-from-global MFMA fragment loads regress vs
// LDS-staged ds_read_b128 fragments, even when perfectly coalesced/tiled --
// L1 thrash + vmcnt latency beats the LDS-bank cost. Keep fragments in LDS.

typedef unsigned short ushort_t;
typedef __attribute__((ext_vector_type(8))) _Float16 half8;    // 8 f16 (4 VGPRs)
typedef __attribute__((ext_vector_type(2))) __fp16 pkhalf2;    // cvt_pkrtz out
typedef __attribute__((ext_vector_type(4))) float floatx4;     // MFMA C/D
typedef __attribute__((ext_vector_type(8))) ushort_t us8;
typedef __attribute__((ext_vector_type(4))) ushort_t us4;

#define C2SCALE 0.02254211f  // log2(e)/64, folded into Q at projection

__device__ __forceinline__ ushort_t f2h(float x) {  // RNE float->f16
  union { _Float16 h; ushort_t u; } v;
  v.h = (_Float16)x;
  return v.u;
}

#if __has_builtin(__builtin_amdgcn_exp2f)
#define EXP2F(x) __builtin_amdgcn_exp2f(x)
#else
#define EXP2F(x) exp2f(x)
#endif

// ---------------------------------------------------------------------------
// fused fp32 -> f16 cast for inp (2048 blocks) + 4 weight mats (1024 blocks)
// ---------------------------------------------------------------------------
__global__ __launch_bounds__(256) void cast_all(
    const float* __restrict__ inp, ushort_t* __restrict__ Xf,
    const float* __restrict__ w0, const float* __restrict__ w1,
    const float* __restrict__ w2, const float* __restrict__ w3,
    ushort_t* __restrict__ d0, ushort_t* __restrict__ d1,
    ushort_t* __restrict__ d2, ushort_t* __restrict__ d3) {
  const int bid = blockIdx.x;
  const float* s;
  ushort_t* d;
  int blk;
  if (bid < 2048) {
    s = inp; d = Xf; blk = bid;
  } else {
    const int seg = (bid - 2048) >> 8;
    blk = (bid - 2048) & 255;
    switch (seg) {
      case 0: s = w0; d = d0; break;
      case 1: s = w1; d = d1; break;
      case 2: s = w2; d = d2; break;
      default: s = w3; d = d3; break;
    }
  }
  const int i = (blk * 256 + threadIdx.x) * 4;
  const float4 v = *(const float4*)(s + i);
  us4 o;
  o[0] = f2h(v.x); o[1] = f2h(v.y); o[2] = f2h(v.z); o[3] = f2h(v.w);
  *(us4*)(d + i) = o;
}

// ---------------------------------------------------------------------------
// Fused QKV single-plane f16 MFMA NT GEMM, LDS-staged, BK=64, 3 blocks/CU.
// 64o x 128n tile. z=0: Q -> f16 (E,N) scaled by C2SCALE; z=1: K -> (N,E);
// z=2: V -> (E,N).
// ---------------------------------------------------------------------------
__global__ __launch_bounds__(256, 3) void gemm_qkv(
    const ushort_t* __restrict__ WQf, const float* __restrict__ WQb,
    const ushort_t* __restrict__ WKf, const float* __restrict__ WKb,
    const ushort_t* __restrict__ WVf, const float* __restrict__ WVb,
    const ushort_t* __restrict__ Xf, ushort_t* __restrict__ Qb,
    ushort_t* __restrict__ Kb, ushort_t* __restrict__ Vb) {
  __shared__ __align__(16) char smem[27648];
  ushort_t(*Ws)[72] = (ushort_t(*)[72])smem;           // [64][72]
  ushort_t(*Xs)[72] = (ushort_t(*)[72])(smem + 9216);  // [128][72]

  const int tid = threadIdx.x;
  const int w = tid >> 6, lane = tid & 63, quad = lane >> 4, l16 = lane & 15;
  const int o0 = blockIdx.y * 64, n0 = blockIdx.x * 128, z = blockIdx.z;
  const int wr = tid >> 2, wseg = (tid & 3) * 16;  // W stage: 64 rows x 16 k
  const int xr = tid >> 1, xseg = (tid & 1) * 32;  // X stage: 128 rows x 32 k

  const ushort_t* Wf = (z == 0) ? WQf : (z == 1) ? WKf : WVf;
  const float* bias = (z == 0) ? WQb : (z == 1) ? WKb : WVb;

  floatx4 acc[4][2];
#pragma unroll
  for (int ot = 0; ot < 4; ++ot)
#pragma unroll
    for (int nt = 0; nt < 2; ++nt) {
      acc[ot][nt][0] = 0.f; acc[ot][nt][1] = 0.f;
      acc[ot][nt][2] = 0.f; acc[ot][nt][3] = 0.f;
    }

  for (int k0 = 0; k0 < EDIM; k0 += 64) {
    const us8 w0 = *(const us8*)(Wf + (o0 + wr) * 512 + k0 + wseg);
    const us8 w1 = *(const us8*)(Wf + (o0 + wr) * 512 + k0 + wseg + 8);
    us8 xv[4];
#pragma unroll
    for (int j = 0; j < 4; ++j)
      xv[j] = *(const us8*)(Xf + (n0 + xr) * 512 + k0 + xseg + j * 8);
    __syncthreads();  // previous iteration's LDS reads complete
    *(us8*)&Ws[wr][wseg] = w0;
    *(us8*)&Ws[wr][wseg + 8] = w1;
#pragma unroll
    for (int j = 0; j < 4; ++j) *(us8*)&Xs[xr][xseg + j * 8] = xv[j];
    __syncthreads();

    half8 a[2][4], b[2][2];
#pragma unroll
    for (int kh = 0; kh < 2; ++kh) {
#pragma unroll
      for (int ot = 0; ot < 4; ++ot)
        a[kh][ot] = *(const half8*)&Ws[ot * 16 + l16][kh * 32 + quad * 8];
#pragma unroll
      for (int nt = 0; nt < 2; ++nt)
        b[kh][nt] =
            *(const half8*)&Xs[w * 32 + nt * 16 + l16][kh * 32 + quad * 8];
    }
#pragma unroll
    for (int kh = 0; kh < 2; ++kh)
#pragma unroll
      for (int ot = 0; ot < 4; ++ot)
#pragma unroll
        for (int nt = 0; nt < 2; ++nt)
          acc[ot][nt] = __builtin_amdgcn_mfma_f32_16x16x32_f16(
              a[kh][ot], b[kh][nt], acc[ot][nt], 0, 0, 0);
  }

  __syncthreads();  // staging reads done; smem reused for epilogue
  float bo[4][4];
#pragma unroll
  for (int ot = 0; ot < 4; ++ot)
#pragma unroll
    for (int r = 0; r < 4; ++r)
      bo[ot][r] = bias[o0 + ot * 16 + quad * 4 + r];

  if (z != 1) {  // f16 (E,N): Q (scaled) or V
    ushort_t(*Cs)[136] = (ushort_t(*)[136])smem;
    const float scale = (z == 0) ? C2SCALE : 1.0f;
#pragma unroll
    for (int ot = 0; ot < 4; ++ot)
#pragma unroll
      for (int nt = 0; nt < 2; ++nt)
#pragma unroll
        for (int r = 0; r < 4; ++r)
          Cs[ot * 16 + quad * 4 + r][w * 32 + nt * 16 + l16] =
              f2h((acc[ot][nt][r] + bo[ot][r]) * scale);
    __syncthreads();
    ushort_t* C = (z == 0) ? Qb : Vb;
    const int row = tid >> 2, seg = (tid & 3) * 32;
#pragma unroll
    for (int j = 0; j < 4; ++j)
      *(us8*)(C + (o0 + row) * 4096 + n0 + seg + j * 8) =
          *(const us8*)&Cs[row][seg + j * 8];
  } else {  // f16 (N,E): K
    ushort_t(*Cs)[72] = (ushort_t(*)[72])smem;
#pragma unroll
    for (int ot = 0; ot < 4; ++ot)
#pragma unroll
      for (int nt = 0; nt < 2; ++nt)
#pragma unroll
        for (int r = 0; r < 4; ++r)
          Cs[w * 32 + nt * 16 + l16][ot * 16 + quad * 4 + r] =
              f2h(acc[ot][nt][r] + bo[ot][r]);
    __syncthreads();
    const int row = tid >> 1, seg = (tid & 1) * 32;
#pragma unroll
    for (int j = 0; j < 4; ++j)
      *(us8*)(Kb + (n0 + row) * 512 + o0 + seg + j * 8) =
          *(const us8*)&Cs[row][seg + j * 8];
  }
}

// ---------------------------------------------------------------------------
// Output projection with FUSED combine: B-operand rows are
// Z[n][e] = (Zp0[n][e] + Zp1[n][e]) / (L0[h][n] + L1[h][n]), h = e>>6.
// Each BK=64 step spans exactly one head -> divisor uniform per (row, iter).
// fp32 (N,E) out. 64o x 64n tile, 512 blocks.
// ---------------------------------------------------------------------------
__global__ __launch_bounds__(256, 2) void gemm_out(
    const ushort_t* __restrict__ Wf, const ushort_t* __restrict__ Zp,
    const float* __restrict__ Lp, const float* __restrict__ bias,
    float* __restrict__ C) {
  __shared__ __align__(16) char smem[18432];
  ushort_t(*Ws)[72] = (ushort_t(*)[72])smem;           // [64][72]
  ushort_t(*Xs)[72] = (ushort_t(*)[72])(smem + 9216);  // [64][72]

  const int tid = threadIdx.x;
  const int w = tid >> 6, lane = tid & 63, quad = lane >> 4, l16 = lane & 15;
  const int o0 = blockIdx.y * 64, n0 = blockIdx.x * 64;
  const int lr = tid >> 2, lseg = (tid & 3) * 16;

  floatx4 acc[4];
#pragma unroll
  for (int ot = 0; ot < 4; ++ot) {
    acc[ot][0] = 0.f; acc[ot][1] = 0.f; acc[ot][2] = 0.f; acc[ot][3] = 0.f;
  }

  for (int k0 = 0; k0 < EDIM; k0 += 64) {
    const int hh = k0 >> 6;
    const us8 w0 = *(const us8*)(Wf + (o0 + lr) * 512 + k0 + lseg);
    const us8 w1 = *(const us8*)(Wf + (o0 + lr) * 512 + k0 + lseg + 8);
    const half8 z00 = *(const half8*)(Zp + (n0 + lr) * 512 + k0 + lseg);
    const half8 z01 = *(const half8*)(Zp + (n0 + lr) * 512 + k0 + lseg + 8);
    const half8 z10 =
        *(const half8*)(Zp + 2097152 + (n0 + lr) * 512 + k0 + lseg);
    const half8 z11 =
        *(const half8*)(Zp + 2097152 + (n0 + lr) * 512 + k0 + lseg + 8);
    const float inv = 1.0f / (Lp[hh * 4096 + n0 + lr] +
                              Lp[32768 + hh * 4096 + n0 + lr]);
    us8 x0, x1;
#pragma unroll
    for (int j = 0; j < 8; ++j) {
      x0[j] = f2h(((float)z00[j] + (float)z10[j]) * inv);
      x1[j] = f2h(((float)z01[j] + (float)z11[j]) * inv);
    }
    __syncthreads();
    *(us8*)&Ws[lr][lseg] = w0;
    *(us8*)&Ws[lr][lseg + 8] = w1;
    *(us8*)&Xs[lr][lseg] = x0;
    *(us8*)&Xs[lr][lseg + 8] = x1;
    __syncthreads();

    half8 a[2][4], b[2];
#pragma unroll
    for (int kh = 0; kh < 2; ++kh) {
#pragma unroll
      for (int ot = 0; ot < 4; ++ot)
        a[kh][ot] = *(const half8*)&Ws[ot * 16 + l16][kh * 32 + quad * 8];
      b[kh] = *(const half8*)&Xs[w * 16 + l16][kh * 32 + quad * 8];
    }
#pragma unroll
    for (int kh = 0; kh < 2; ++kh)
#pragma unroll
      for (int ot = 0; ot < 4; ++ot)
        acc[ot] = __builtin_amdgcn_mfma_f32_16x16x32_f16(a[kh][ot], b[kh],
                                                         acc[ot], 0, 0, 0);
  }

  __syncthreads();
  float(*Cs)[68] = (float(*)[68])smem;
#pragma unroll
  for (int ot = 0; ot < 4; ++ot) {
    floatx4 v = acc[ot];
#pragma unroll
    for (int r = 0; r < 4; ++r) v[r] += bias[o0 + ot * 16 + quad * 4 + r];
    *(floatx4*)&Cs[w * 16 + l16][ot * 16 + quad * 4] = v;
  }
  __syncthreads();
  const int row = tid >> 2, seg = (tid & 3) * 16;
#pragma unroll
  for (int j = 0; j < 4; ++j)
    *(float4*)(C + (n0 + row) * 512 + o0 + seg + j * 4) =
        *(const float4*)&Cs[row][seg + j * 4];
}

// ---------------------------------------------------------------------------
// V (f16, scrambled (E,N)) -> Vt[h][d][m]
// ---------------------------------------------------------------------------
__global__ __launch_bounds__(256) void transpose_v(
    const ushort_t* __restrict__ Vb, ushort_t* __restrict__ Vt) {
  __shared__ ushort_t Ts[64][72];
  const int tid = threadIdx.x;
  const int h = blockIdx.y;
  const int m0 = blockIdx.x * 64;
  const ushort_t* src = Vb + h * 262144 + m0 * 64;
  {
    const int r = tid >> 2, c = (tid & 3) << 4;
    const us8 a = *(const us8*)(src + r * 64 + c);
    const us8 b = *(const us8*)(src + r * 64 + c + 8);
    *(us8*)&Ts[r][c] = a;
    *(us8*)&Ts[r][c + 8] = b;
  }
  __syncthreads();
  const int d = tid >> 2, r0 = (tid & 3) << 4;
  us8 o0, o1;
#pragma unroll
  for (int j = 0; j < 8; ++j) {
    o0[j] = Ts[r0 + j][d];
    o1[j] = Ts[r0 + 8 + j][d];
  }
  ushort_t* dst = Vt + h * 262144 + d * 4096 + m0 + r0;
  *(us8*)(dst) = o0;
  *(us8*)(dst + 8) = o1;
}

// ---------------------------------------------------------------------------
// Flash attention (R7 known-good): f16 MFMA, transposed-score, LDS-staged
// K/V, max-free softmax (Q pre-scaled by log2(e)/64), rowsum via ones-MFMA
// (consistent with stored f16 P), split-K 2, f16 Z^T partials.
// ---------------------------------------------------------------------------
__global__ __launch_bounds__(256, 2) void attn_mfma(
    const ushort_t* __restrict__ Qb, const ushort_t* __restrict__ Kb,
    const ushort_t* __restrict__ Vt, ushort_t* __restrict__ Zp,
    float* __restrict__ Lp) {
  __shared__ __align__(16) ushort_t Ks[128][72];     // K chunk [m][d]
  __shared__ __align__(16) ushort_t Vts[64][136];    // V^T chunk [d][m]
  __shared__ __align__(16) ushort_t Ps[8][16][136];  // per (w,qt): P [n][m]

  const int tid = threadIdx.x;
  const int w = tid >> 6;
  const int lane = tid & 63;
  const int quad = lane >> 4;
  const int l16 = lane & 15;
  const int h = blockIdx.y;
  const int n0 = blockIdx.x * 128;
  const int z = blockIdx.z;
  const int mbase = z * (NSEQ / 2);

  half8 qf[2][2];
#pragma unroll
  for (int qt = 0; qt < 2; ++qt) {
    const ushort_t* qsrc = Qb + h * 262144 + (n0 + w * 32 + qt * 16 + l16) * 64;
    qf[qt][0] = *(const half8*)(qsrc + quad * 8);
    qf[qt][1] = *(const half8*)(qsrc + 32 + quad * 8);
  }

  half8 ones;
#pragma unroll
  for (int j = 0; j < 8; ++j) ones[j] = (_Float16)1.0f;

  floatx4 zacc[2][4];
  floatx4 sumacc[2];
#pragma unroll
  for (int qt = 0; qt < 2; ++qt) {
    sumacc[qt][0] = 0.f; sumacc[qt][1] = 0.f;
    sumacc[qt][2] = 0.f; sumacc[qt][3] = 0.f;
#pragma unroll
    for (int dt = 0; dt < 4; ++dt) {
      zacc[qt][dt][0] = 0.f; zacc[qt][dt][1] = 0.f;
      zacc[qt][dt][2] = 0.f; zacc[qt][dt][3] = 0.f;
    }
  }

  const int kr = tid >> 2;
  const int kc = (tid & 3) << 4;
  const int vd = tid >> 2;
  const int vm = (tid & 3) << 5;

  for (int m0 = 0; m0 < NSEQ / 2; m0 += 128) {
    const ushort_t* ksrc = Kb + h * 262144 + (mbase + m0) * 64;
    const ushort_t* vsrc = Vt + h * 262144 + vd * 4096 + mbase + m0 + vm;
    us8 kst[4], vst[4];
    kst[0] = *(const us8*)(ksrc + kr * 64 + kc);
    kst[1] = *(const us8*)(ksrc + kr * 64 + kc + 8);
    kst[2] = *(const us8*)(ksrc + (64 + kr) * 64 + kc);
    kst[3] = *(const us8*)(ksrc + (64 + kr) * 64 + kc + 8);
#pragma unroll
    for (int j = 0; j < 4; ++j) vst[j] = *(const us8*)(vsrc + j * 8);

    __syncthreads();  // previous chunk's LDS reads complete
    *(us8*)&Ks[kr][kc] = kst[0];
    *(us8*)&Ks[kr][kc + 8] = kst[1];
    *(us8*)&Ks[64 + kr][kc] = kst[2];
    *(us8*)&Ks[64 + kr][kc + 8] = kst[3];
#pragma unroll
    for (int j = 0; j < 4; ++j) *(us8*)&Vts[vd][vm + j * 8] = vst[j];
    __syncthreads();

    half8 kf0[8], kf1[8];
#pragma unroll
    for (int mt = 0; mt < 8; ++mt) {
      kf0[mt] = *(const half8*)&Ks[mt * 16 + l16][quad * 8];
      kf1[mt] = *(const half8*)&Ks[mt * 16 + l16][32 + quad * 8];
    }

#pragma unroll
    for (int qt = 0; qt < 2; ++qt) {
#pragma unroll
      for (int mt = 0; mt < 8; ++mt) {
        floatx4 s = {0.f, 0.f, 0.f, 0.f};
        s = __builtin_amdgcn_mfma_f32_16x16x32_f16(kf0[mt], qf[qt][0], s, 0, 0, 0);
        s = __builtin_amdgcn_mfma_f32_16x16x32_f16(kf1[mt], qf[qt][1], s, 0, 0, 0);
        union { pkhalf2 h; unsigned u; } p01, p23;
        p01.h = __builtin_amdgcn_cvt_pkrtz(EXP2F(s[0]), EXP2F(s[1]));
        p23.h = __builtin_amdgcn_cvt_pkrtz(EXP2F(s[2]), EXP2F(s[3]));
        *(unsigned*)&Ps[w * 2 + qt][l16][mt * 16 + quad * 4] = p01.u;
        *(unsigned*)&Ps[w * 2 + qt][l16][mt * 16 + quad * 4 + 2] = p23.u;
      }
    }
    // per-wave Ps: same-wave LDS RAW ordered via lgkmcnt (no barrier)

#pragma unroll
    for (int kc2 = 0; kc2 < 4; ++kc2) {
      const half8 pf0 = *(const half8*)&Ps[w * 2][l16][kc2 * 32 + quad * 8];
      const half8 pf1 = *(const half8*)&Ps[w * 2 + 1][l16][kc2 * 32 + quad * 8];
      sumacc[0] = __builtin_amdgcn_mfma_f32_16x16x32_f16(ones, pf0, sumacc[0], 0, 0, 0);
      sumacc[1] = __builtin_amdgcn_mfma_f32_16x16x32_f16(ones, pf1, sumacc[1], 0, 0, 0);
#pragma unroll
      for (int dt = 0; dt < 4; ++dt) {
        const half8 vf = *(const half8*)&Vts[dt * 16 + l16][kc2 * 32 + quad * 8];
        zacc[0][dt] = __builtin_amdgcn_mfma_f32_16x16x32_f16(vf, pf0, zacc[0][dt], 0, 0, 0);
        zacc[1][dt] = __builtin_amdgcn_mfma_f32_16x16x32_f16(vf, pf1, zacc[1][dt], 0, 0, 0);
      }
    }
  }

  // ---- partial epilogue: Z^T partials as f16, row-sums fp32 ----
#pragma unroll
  for (int qt = 0; qt < 2; ++qt) {
    const int n = n0 + w * 32 + qt * 16 + l16;
    ushort_t* dst = Zp + z * 2097152 + n * EDIM + h * 64;
#pragma unroll
    for (int dt = 0; dt < 4; ++dt) {
      us4 o;
#pragma unroll
      for (int r = 0; r < 4; ++r) o[r] = f2h(zacc[qt][dt][r]);
      *(us4*)(dst + dt * 16 + quad * 4) = o;
    }
    if (quad == 0) Lp[z * 32768 + h * 4096 + n] = sumacc[qt][0];
  }
}

extern "C" void kernel_launch(void* const* d_in, const int* in_sizes, int n_in,
                              void* d_out, int out_size, void* d_ws,
                              size_t ws_size, hipStream_t stream) {
  const float* inp = (const float*)d_in[0];
  const float* WKw = (const float*)d_in[1];
  const float* WKb = (const float*)d_in[2];
  const float* WQw = (const float*)d_in[3];
  const float* WQb = (const float*)d_in[4];
  const float* WVw = (const float*)d_in[5];
  const float* WVb = (const float*)d_in[6];
  const float* WZw = (const float*)d_in[7];
  const float* WZb = (const float*)d_in[8];

  char* ws = (char*)d_ws;
  const size_t MB = 1 << 20;
  ushort_t* Xf = (ushort_t*)(ws);                        // 4MB
  ushort_t* WQf = (ushort_t*)(ws + 4 * MB);              // 512KB each
  ushort_t* WKf = (ushort_t*)(ws + 4 * MB + 512 * 1024);
  ushort_t* WVf = (ushort_t*)(ws + 5 * MB);
  ushort_t* WZf = (ushort_t*)(ws + 5 * MB + 512 * 1024);
  ushort_t* Qb = (ushort_t*)(ws + 6 * MB);    // 4MB f16 (E,N) scrambled, *C2
  ushort_t* Kb = (ushort_t*)(ws + 10 * MB);   // 4MB f16 (N,E)
  ushort_t* Vb = (ushort_t*)(ws + 14 * MB);   // 4MB f16 (E,N)
  ushort_t* Vtb = (ushort_t*)(ws + 18 * MB);  // 4MB f16 [h][d][m]
  ushort_t* Zp = (ushort_t*)(ws + 22 * MB);   // 8MB: [2][4096][512] f16
  float* Lp = (float*)(ws + 30 * MB);         // 256KB: [2][8][4096]

  cast_all<<<3072, 256, 0, stream>>>(inp, Xf, WKw, WQw, WVw, WZw, WKf, WQf,
                                     WVf, WZf);

  gemm_qkv<<<dim3(NSEQ / 128, EDIM / 64, 3), 256, 0, stream>>>(
      WQf, WQb, WKf, WKb, WVf, WVb, Xf, Qb, Kb, Vb);

  transpose_v<<<dim3(NSEQ / 64, NHEAD), 256, 0, stream>>>(Vb, Vtb);

  attn_mfma<<<dim3(NSEQ / 128, NHEAD, 2), 256, 0, stream>>>(Qb, Kb, Vtb, Zp,
                                                            Lp);

  gemm_out<<<dim3(NSEQ / 64, EDIM / 64), 256, 0, stream>>>(WZf, Zp, Lp, WZb,
                                                           (float*)d_out);
}